// Round 9
// baseline (37.742 us; speedup 1.0000x reference)
//
#include <hip/hip_runtime.h>
#include <math.h>

#define FDIM  50
#define EDIM  16
#define ADIM  16
#define NPAIR 1225
#define BROWS 32        // batch rows per row-group (MFMA cols)
#define NTHREADS 1024
#define NWAVE 16
#define NSTRIDE 32      // pair stride: 2 blocks x 16 waves per row-group
#define NPAD  (NPAIR + 2 * NSTRIDE)
#define FBLK  1024      // bytes per f-block in LDS: [lane64][16B]

typedef _Float16 half8v __attribute__((ext_vector_type(8)));
typedef __fp16   h16x8  __attribute__((ext_vector_type(8)));
typedef float    f32x16 __attribute__((ext_vector_type(16)));

__device__ inline f32x16 mfma32x32x16f16(half8v a, half8v b, f32x16 c) {
    return __builtin_amdgcn_mfma_f32_32x32x16_f16(
        __builtin_bit_cast(h16x8, a), __builtin_bit_cast(h16x8, b), c, 0, 0, 0);
}

// ws layout (floats): [g:256][h:2][r:32][{num,den}]  = 32768 floats
//                     then ylin[8192]                = 8192 floats
#define WS_YLIN 32768

__global__ __launch_bounds__(NTHREADS) void afm_fwd(
    const int*   __restrict__ feat_index,
    const float* __restrict__ feat_value,
    const float* __restrict__ emb_table,
    const float* __restrict__ attn_w,
    const float* __restrict__ attn_b,
    const float* __restrict__ attn_h,
    const float* __restrict__ attn_p,
    const float* __restrict__ lin_w,
    const float* __restrict__ lin_b,
    float*       __restrict__ ws)
{
    // [f][lane64][8 f16]: lane = kh*32 + b, holds e = kh*8 .. kh*8+7 for batch col b
    __shared__ __align__(16) _Float16 embLds[FDIM * 512];   // 51200 B
    __shared__ unsigned ijLds[NPAD];
    __shared__ float    redLds[NWAVE][BROWS][2];            // [wv][b][{num,den}]
    __shared__ float    ylinLds[BROWS];
    __shared__ float    lwLds[FDIM];

    const int t    = threadIdx.x;
    const int lane = t & 63;
    const int wv   = t >> 6;
    const int hi   = lane >> 5;    // k-half (and num/den role)
    const int col  = lane & 31;    // batch col (B) / D-row index for A
    const int g    = blockIdx.x >> 1;
    const int h    = blockIdx.x & 1;
    const int b0   = g * BROWS;

    if (t < FDIM) lwLds[t] = lin_w[t];

    // ---- ij offset table (padded; tail repeats last pair for safe prefetch) ----
    for (int p = t; p < NPAD; p += NTHREADS) {
        int pc = (p < NPAIR) ? p : NPAIR - 1;
        float tq = 9801.0f - 8.0f * (float)pc;
        int ii = (int)((99.0f - sqrtf(tq)) * 0.5f);
        ii = max(0, min(48, ii));
        while (ii < 48 && (49*(ii+1) - (((ii+1)*ii)>>1)) <= pc) ++ii;
        while (ii > 0  && (49*ii - ((ii*(ii-1))>>1)) > pc) --ii;
        int q  = 49*ii - ((ii*(ii-1))>>1);
        int jj = ii + 1 + (pc - q);
        ijLds[p] = ((unsigned)(ii*FBLK) << 16) | (unsigned)(jj*FBLK);
    }

    // ---- stage emb: lane l -> (b=l&31, kh=l>>5) ----
    for (int f = t >> 6; f < FDIM; f += NWAVE) {
        int   fi = feat_index[(b0 + col) * FDIM + f];
        float fv = feat_value[(b0 + col) * FDIM + f];
        const float4* tr = (const float4*)(emb_table + (size_t)fi * EDIM + hi * 8);
        float4 v0 = tr[0], v1 = tr[1];
        half8v hh;
        hh[0] = (_Float16)(v0.x * fv); hh[1] = (_Float16)(v0.y * fv);
        hh[2] = (_Float16)(v0.z * fv); hh[3] = (_Float16)(v0.w * fv);
        hh[4] = (_Float16)(v1.x * fv); hh[5] = (_Float16)(v1.y * fv);
        hh[6] = (_Float16)(v1.z * fv); hh[7] = (_Float16)(v1.w * fv);
        *(half8v*)&embLds[f * 512 + lane * 8] = hh;
    }
    __syncthreads();

    // ---- y_lin (only h==0 block stores): threads 0..511: b = t>>4, e = t&15 ----
    if (h == 0 && t < 512) {
        int bb = t >> 4, e = t & 15;
        int off = (e >> 3) * 256 + bb * 8 + (e & 7);
        float acc = lin_b[0];
        #pragma unroll
        for (int f = 0; f < FDIM; ++f)
            acc = fmaf((float)embLds[f * 512 + off], lwLds[f], acc);
        acc = fmaxf(acc, 0.0f);
        acc += __shfl_xor(acc, 1);
        acc += __shfl_xor(acc, 2);
        acc += __shfl_xor(acc, 4);
        acc += __shfl_xor(acc, 8);
        if (e == 0) ylinLds[bb] = acc;
    }

    // ---- loop-invariant fragments ----
    // MFMA: D[m][b] = sum_e A[m][e]*ewp[e][b] (+C). A rows: m<16 -> W^T, m==16 -> p, else 0.
    half8v fragA1;
    #pragma unroll
    for (int e = 0; e < 8; ++e) {
        int k = hi * 8 + e;
        float av = (col < ADIM) ? attn_w[k * ADIM + col]
                 : (col == ADIM) ? attn_p[k] : 0.0f;
        fragA1[e] = (_Float16)av;
    }
    // C/D row map: r = (reg&3) + 8*(reg>>2) + 4*hi
    float hrow[8];
    f32x16 biasC;
    #pragma unroll
    for (int reg = 0; reg < 8; ++reg) {
        int r = (reg & 3) + 8 * (reg >> 2) + 4 * hi;
        hrow[reg]  = attn_h[r] * 1.44269504f;   // fold log2(e) -> exp2 at the end
        biasC[reg] = attn_b[r];
        biasC[reg + 8] = 0.f;
    }

    const char* ebase = (const char*)embLds;
    const unsigned laddr = (unsigned)lane * 16u;

    // ---- software-pipelined pair loop: this block owns p = (h*16+wv) + 32k ----
    const int W = h * NWAVE + wv;
    float num = 0.f, den = 0.f;
    unsigned u0   = ijLds[W];
    half8v   ei   = *(const half8v*)(ebase + (u0 >> 16)     + laddr);
    half8v   ej   = *(const half8v*)(ebase + (u0 & 0xffffu) + laddr);
    unsigned unxt = ijLds[W + NSTRIDE];

    #pragma unroll 2
    for (int p = W; p < NPAIR; p += NSTRIDE) {
        half8v ei_n = *(const half8v*)(ebase + (unxt >> 16)     + laddr);
        half8v ej_n = *(const half8v*)(ebase + (unxt & 0xffffu) + laddr);
        unsigned u2 = ijLds[p + 2 * NSTRIDE];

        half8v prod = ei * ej;                         // B fragment (k=hi*8+e, col=b)
        f32x16 acc1 = mfma32x32x16f16(fragA1, prod, biasC);

        float s0 = 0.f, s1 = 0.f;
        #pragma unroll
        for (int reg = 0; reg < 4; ++reg) {
            s0 = fmaf(fmaxf(acc1[reg],     0.f), hrow[reg],     s0);
            s1 = fmaf(fmaxf(acc1[reg + 4], 0.f), hrow[reg + 4], s1);
        }
        float s = s0 + s1;
        s += __shfl_xor(s, 32);
        float sc = __builtin_amdgcn_exp2f(s);
        if (hi) den += sc;
        else    num = fmaf(sc, acc1[8], num);          // acc1[8] = u (row 16)

        ei = ei_n; ej = ej_n; unxt = u2;
    }

    if (hi) redLds[wv][col][1] = den;
    else    redLds[wv][col][0] = num;
    __syncthreads();

    if (t < BROWS) {
        float nn = 0.f, dd = 0.f;
        #pragma unroll
        for (int w = 0; w < NWAVE; ++w) { nn += redLds[w][t][0]; dd += redLds[w][t][1]; }
        float* dst = ws + ((g * 2 + h) * BROWS + t) * 2;
        dst[0] = nn; dst[1] = dd;
        if (h == 0) ws[WS_YLIN + b0 + t] = ylinLds[t];
    }
}

__global__ __launch_bounds__(256) void afm_combine(const float* __restrict__ ws,
                                                   float* __restrict__ out) {
    int b = blockIdx.x * 256 + threadIdx.x;
    int g = b >> 5, r = b & 31;
    const float* base = ws + g * 128;
    float nn = base[r * 2]     + base[64 + r * 2];
    float dd = base[r * 2 + 1] + base[64 + r * 2 + 1];
    out[b] = nn / dd + ws[WS_YLIN + b];
}

extern "C" void kernel_launch(void* const* d_in, const int* in_sizes, int n_in,
                              void* d_out, int out_size, void* d_ws, size_t ws_size,
                              hipStream_t stream) {
    const int*   feat_index = (const int*)  d_in[0];
    const float* feat_value = (const float*)d_in[1];
    const float* emb_table  = (const float*)d_in[2];
    const float* attn_w     = (const float*)d_in[3];
    const float* attn_b     = (const float*)d_in[4];
    const float* attn_h     = (const float*)d_in[5];
    const float* attn_p     = (const float*)d_in[6];
    const float* lin_w      = (const float*)d_in[7];
    const float* lin_b      = (const float*)d_in[8];
    float* wsf  = (float*)d_ws;
    float* outp = (float*)d_out;

    dim3 grid(out_size / BROWS * 2);   // 512 blocks: 2 per 32-row group
    dim3 block(NTHREADS);
    afm_fwd<<<grid, block, 0, stream>>>(feat_index, feat_value, emb_table,
                                        attn_w, attn_b, attn_h, attn_p,
                                        lin_w, lin_b, wsf);
    afm_combine<<<dim3(out_size / 256), dim3(256), 0, stream>>>(wsf, outp);
}

// Round 10
// 29.832 us; speedup vs baseline: 1.2652x; 1.2652x over previous
//
#include <hip/hip_runtime.h>
#include <math.h>

#define FDIM  50
#define EDIM  16
#define ADIM  16
#define NPAIR 1225
#define BROWS 32        // batch rows per block (MFMA cols)
#define NTHREADS 1024
#define NWAVE 16
#define NPAD  (NPAIR + 2 * NWAVE)   // padded ij table for prefetch overread
#define FBLK  1024      // bytes per f-block in LDS: [lane64][16B]

typedef _Float16 half8v __attribute__((ext_vector_type(8)));
typedef __fp16   h16x8  __attribute__((ext_vector_type(8)));
typedef __fp16   h16x2  __attribute__((ext_vector_type(2)));
typedef float    f32x16 __attribute__((ext_vector_type(16)));

__device__ inline f32x16 mfma32x32x16f16(half8v a, half8v b, f32x16 c) {
    return __builtin_amdgcn_mfma_f32_32x32x16_f16(
        __builtin_bit_cast(h16x8, a), __builtin_bit_cast(h16x8, b), c, 0, 0, 0);
}

__global__ __launch_bounds__(NTHREADS) void afm_fwd(
    const int*   __restrict__ feat_index,
    const float* __restrict__ feat_value,
    const float* __restrict__ emb_table,
    const float* __restrict__ attn_w,
    const float* __restrict__ attn_b,
    const float* __restrict__ attn_h,
    const float* __restrict__ attn_p,
    const float* __restrict__ lin_w,
    const float* __restrict__ lin_b,
    float*       __restrict__ out)
{
    // [f][lane64][8 f16]: lane = kh*32 + b, holds e = kh*8 .. kh*8+7 for batch col b
    __shared__ __align__(16) _Float16 embLds[FDIM * 512];   // 51200 B
    __shared__ unsigned ijLds[NPAD];
    __shared__ float    redLds[NWAVE][BROWS][2];            // [wv][b][{num,den}]
    __shared__ float    ylinLds[BROWS];
    __shared__ float    lwLds[FDIM];

    const int t    = threadIdx.x;
    const int lane = t & 63;
    const int wv   = t >> 6;
    const int hi   = lane >> 5;    // k-half (and num/den role)
    const int col  = lane & 31;    // batch col (B) / D-row index for A
    const int b0   = blockIdx.x * BROWS;

    if (t < FDIM) lwLds[t] = lin_w[t];

    // ---- ij offset table (padded; tail repeats last pair for safe prefetch) ----
    for (int p = t; p < NPAD; p += NTHREADS) {
        int pc = (p < NPAIR) ? p : NPAIR - 1;
        float tq = 9801.0f - 8.0f * (float)pc;
        int ii = (int)((99.0f - sqrtf(tq)) * 0.5f);
        ii = max(0, min(48, ii));
        while (ii < 48 && (49*(ii+1) - (((ii+1)*ii)>>1)) <= pc) ++ii;
        while (ii > 0  && (49*ii - ((ii*(ii-1))>>1)) > pc) --ii;
        int q  = 49*ii - ((ii*(ii-1))>>1);
        int jj = ii + 1 + (pc - q);
        ijLds[p] = ((unsigned)(ii*FBLK) << 16) | (unsigned)(jj*FBLK);
    }

    // ---- stage emb: lane l -> (b=l&31, kh=l>>5) ----
    for (int f = t >> 6; f < FDIM; f += NWAVE) {
        int   fi = feat_index[(b0 + col) * FDIM + f];
        float fv = feat_value[(b0 + col) * FDIM + f];
        const float4* tr = (const float4*)(emb_table + (size_t)fi * EDIM + hi * 8);
        float4 v0 = tr[0], v1 = tr[1];
        half8v hh;
        hh[0] = (_Float16)(v0.x * fv); hh[1] = (_Float16)(v0.y * fv);
        hh[2] = (_Float16)(v0.z * fv); hh[3] = (_Float16)(v0.w * fv);
        hh[4] = (_Float16)(v1.x * fv); hh[5] = (_Float16)(v1.y * fv);
        hh[6] = (_Float16)(v1.z * fv); hh[7] = (_Float16)(v1.w * fv);
        *(half8v*)&embLds[f * 512 + lane * 8] = hh;
    }
    __syncthreads();

    // ---- y_lin: threads 0..511: b = t>>4, e = t&15 ----
    if (t < 512) {
        int bb = t >> 4, e = t & 15;
        int off = (e >> 3) * 256 + bb * 8 + (e & 7);
        float acc = lin_b[0];
        #pragma unroll
        for (int f = 0; f < FDIM; ++f)
            acc = fmaf((float)embLds[f * 512 + off], lwLds[f], acc);
        acc = fmaxf(acc, 0.0f);
        acc += __shfl_xor(acc, 1);
        acc += __shfl_xor(acc, 2);
        acc += __shfl_xor(acc, 4);
        acc += __shfl_xor(acc, 8);
        if (e == 0) ylinLds[bb] = acc;
    }

    // ---- loop-invariant fragments ----
    // MFMA1: D[m][b] = sum_e A[m][e]*ewp[e][b] (+C). A rows: m<16 -> W^T, m==16 -> p, else 0.
    half8v fragA1;
    #pragma unroll
    for (int e = 0; e < 8; ++e) {
        int k = hi * 8 + e;
        float av = (col < ADIM) ? attn_w[k * ADIM + col]
                 : (col == ADIM) ? attn_p[k] : 0.0f;
        fragA1[e] = (_Float16)av;
    }
    // C/D row map: reg r (0..7) holds row (r&3)+8*(r>>2)+4*hi.
    // MFMA2: B2 frag element e (k=hi*8+e) = packed relu(acc1[e]) = P[pi(k)][b],
    //        pi(k) = (e&3)+8*((e>>2)&1)+4*hi  (a bijection of rows 0..15)
    //        -> A2[m][k] = h[pi(k)] * log2e for ALL m; every D2 reg = s[b].
    half8v fragA2;
    f32x16 biasC;
    #pragma unroll
    for (int e = 0; e < 8; ++e) {
        int r = (e & 3) + 8 * (e >> 2) + 4 * hi;
        fragA2[e]  = (_Float16)(attn_h[r] * 1.44269504f);
        biasC[e]   = attn_b[r];
        biasC[e+8] = 0.f;
    }
    f32x16 zeroC;
    #pragma unroll
    for (int r = 0; r < 16; ++r) zeroC[r] = 0.f;

    const char* ebase = (const char*)embLds;
    const unsigned laddr = (unsigned)lane * 16u;

    // ---- software-pipelined pair loop (1-deep prefetch), p = wv + 16k ----
    float num = 0.f, den = 0.f;
    unsigned u0   = ijLds[wv];
    half8v   ei   = *(const half8v*)(ebase + (u0 >> 16)     + laddr);
    half8v   ej   = *(const half8v*)(ebase + (u0 & 0xffffu) + laddr);
    unsigned unxt = ijLds[wv + NWAVE];

    #pragma unroll 2
    for (int p = wv; p < NPAIR; p += NWAVE) {
        half8v ei_n = *(const half8v*)(ebase + (unxt >> 16)     + laddr);
        half8v ej_n = *(const half8v*)(ebase + (unxt & 0xffffu) + laddr);
        unsigned u2 = ijLds[p + 2 * NWAVE];

        half8v prod = ei * ej;                         // B1 fragment (k=hi*8+e, col=b)
        f32x16 acc1 = mfma32x32x16f16(fragA1, prod, biasC);

        // pack regs 0..7 -> fp16, relu, feed MFMA2
        h16x2 q01 = __builtin_amdgcn_cvt_pkrtz(acc1[0], acc1[1]);
        h16x2 q23 = __builtin_amdgcn_cvt_pkrtz(acc1[2], acc1[3]);
        h16x2 q45 = __builtin_amdgcn_cvt_pkrtz(acc1[4], acc1[5]);
        h16x2 q67 = __builtin_amdgcn_cvt_pkrtz(acc1[6], acc1[7]);
        h16x8 pk = __builtin_shufflevector(
                       __builtin_shufflevector(q01, q23, 0, 1, 2, 3),
                       __builtin_shufflevector(q45, q67, 0, 1, 2, 3),
                       0, 1, 2, 3, 4, 5, 6, 7);
        half8v rf = __builtin_bit_cast(half8v, pk);
        half8v zf;
        #pragma unroll
        for (int e = 0; e < 8; ++e) zf[e] = (_Float16)0;
#if __has_builtin(__builtin_elementwise_max)
        rf = __builtin_elementwise_max(rf, zf);        // v_pk_max_f16 x4
#else
        #pragma unroll
        for (int e = 0; e < 8; ++e) rf[e] = rf[e] > (_Float16)0 ? rf[e] : (_Float16)0;
#endif
        f32x16 acc2 = mfma32x32x16f16(fragA2, rf, zeroC);   // every reg = s[b]

        float sc = __builtin_amdgcn_exp2f(acc2[0]);
        if (hi) den += sc;                             // lanes>=32: denominator
        else    num = fmaf(sc, acc1[8], num);          // acc1[8] = u (row 16)

        ei = ei_n; ej = ej_n; unxt = u2;
    }

    if (hi) redLds[wv][col][1] = den;
    else    redLds[wv][col][0] = num;
    __syncthreads();

    if (t < BROWS) {
        float nn = 0.f, dd = 0.f;
        #pragma unroll
        for (int w = 0; w < NWAVE; ++w) { nn += redLds[w][t][0]; dd += redLds[w][t][1]; }
        out[b0 + t] = nn / dd + ylinLds[t];
    }
}

extern "C" void kernel_launch(void* const* d_in, const int* in_sizes, int n_in,
                              void* d_out, int out_size, void* d_ws, size_t ws_size,
                              hipStream_t stream) {
    const int*   feat_index = (const int*)  d_in[0];
    const float* feat_value = (const float*)d_in[1];
    const float* emb_table  = (const float*)d_in[2];
    const float* attn_w     = (const float*)d_in[3];
    const float* attn_b     = (const float*)d_in[4];
    const float* attn_h     = (const float*)d_in[5];
    const float* attn_p     = (const float*)d_in[6];
    const float* lin_w      = (const float*)d_in[7];
    const float* lin_b      = (const float*)d_in[8];
    float* outp = (float*)d_out;

    dim3 grid(out_size / BROWS);   // 256 blocks of 32 batch rows
    dim3 block(NTHREADS);
    afm_fwd<<<grid, block, 0, stream>>>(feat_index, feat_value, emb_table,
                                        attn_w, attn_b, attn_h, attn_p,
                                        lin_w, lin_b, outp);
}

// Round 11
// 28.937 us; speedup vs baseline: 1.3043x; 1.0309x over previous
//
#include <hip/hip_runtime.h>
#include <math.h>

#define FDIM  50
#define EDIM  16
#define ADIM  16
#define NPAIR 1225
#define BROWS 32        // batch rows per block (MFMA cols)
#define NTHREADS 1024
#define NWAVE 16
#define CHUNK 77        // contiguous pairs per wave (last wave: 70)
#define FBLK  1024      // bytes per f-row in LDS: [lane64][16B]

typedef _Float16 half8v __attribute__((ext_vector_type(8)));
typedef __fp16   h16x8  __attribute__((ext_vector_type(8)));
typedef __fp16   h16x2  __attribute__((ext_vector_type(2)));
typedef float    f32x16 __attribute__((ext_vector_type(16)));

__device__ inline f32x16 mfma32x32x16f16(half8v a, half8v b, f32x16 c) {
    return __builtin_amdgcn_mfma_f32_32x32x16_f16(
        __builtin_bit_cast(h16x8, a), __builtin_bit_cast(h16x8, b), c, 0, 0, 0);
}

__global__ __launch_bounds__(NTHREADS) void afm_fwd(
    const int*   __restrict__ feat_index,
    const float* __restrict__ feat_value,
    const float* __restrict__ emb_table,
    const float* __restrict__ attn_w,
    const float* __restrict__ attn_b,
    const float* __restrict__ attn_h,
    const float* __restrict__ attn_p,
    const float* __restrict__ lin_w,
    const float* __restrict__ lin_b,
    float*       __restrict__ out)
{
    // [f][lane64][8 f16]: lane = kh*32 + b, holds e = kh*8..kh*8+7 for batch col b
    // +1 pad row (f=50) for the 1-deep ej prefetch overread
    __shared__ __align__(16) _Float16 embLds[(FDIM + 1) * 512];   // 52224 B
    __shared__ float redLds[NWAVE][BROWS][2];                     // [wv][b][{num,den}]
    __shared__ float ylinLds[BROWS];
    __shared__ float lwLds[FDIM];

    const int t    = threadIdx.x;
    const int lane = t & 63;
    const int wv   = t >> 6;
    const int hi   = lane >> 5;    // k-half (and num/den role)
    const int col  = lane & 31;    // batch col (B) / D-row index for A
    const int b0   = blockIdx.x * BROWS;

    if (t < FDIM) lwLds[t] = lin_w[t];

    // ---- stage emb: lane l -> (b=l&31, kh=l>>5) ----
    for (int f = t >> 6; f < FDIM; f += NWAVE) {
        int   fi = feat_index[(b0 + col) * FDIM + f];
        float fv = feat_value[(b0 + col) * FDIM + f];
        const float4* tr = (const float4*)(emb_table + (size_t)fi * EDIM + hi * 8);
        float4 v0 = tr[0], v1 = tr[1];
        half8v hh;
        hh[0] = (_Float16)(v0.x * fv); hh[1] = (_Float16)(v0.y * fv);
        hh[2] = (_Float16)(v0.z * fv); hh[3] = (_Float16)(v0.w * fv);
        hh[4] = (_Float16)(v1.x * fv); hh[5] = (_Float16)(v1.y * fv);
        hh[6] = (_Float16)(v1.z * fv); hh[7] = (_Float16)(v1.w * fv);
        *(half8v*)&embLds[f * 512 + lane * 8] = hh;
    }
    __syncthreads();

    // ---- y_lin: threads 0..511: b = t>>4, e = t&15 ----
    if (t < 512) {
        int bb = t >> 4, e = t & 15;
        int off = (e >> 3) * 256 + bb * 8 + (e & 7);
        float acc = lin_b[0];
        #pragma unroll
        for (int f = 0; f < FDIM; ++f)
            acc = fmaf((float)embLds[f * 512 + off], lwLds[f], acc);
        acc = fmaxf(acc, 0.0f);
        acc += __shfl_xor(acc, 1);
        acc += __shfl_xor(acc, 2);
        acc += __shfl_xor(acc, 4);
        acc += __shfl_xor(acc, 8);
        if (e == 0) ylinLds[bb] = acc;
    }

    // ---- loop-invariant fragments ----
    // MFMA1: D[m][b] = sum_e A[m][e]*ewp[e][b] (+C). A rows: m<16 -> W^T, m==16 -> p, else 0.
    half8v fragA1;
    #pragma unroll
    for (int e = 0; e < 8; ++e) {
        int k = hi * 8 + e;
        float av = (col < ADIM) ? attn_w[k * ADIM + col]
                 : (col == ADIM) ? attn_p[k] : 0.0f;
        fragA1[e] = (_Float16)av;
    }
    // C/D row map: reg r (0..7) holds row (r&3)+8*(r>>2)+4*hi.
    // MFMA2: B2 elem e (k=hi*8+e) = packed relu(acc1[e]) = P[pi(k)][b],
    //        pi(k) = (e&3)+8*(e>>2)+4*hi  -> A2[m][k] = h[pi(k)]*log2e for all m.
    half8v fragA2;
    f32x16 biasC;
    #pragma unroll
    for (int e = 0; e < 8; ++e) {
        int r = (e & 3) + 8 * (e >> 2) + 4 * hi;
        fragA2[e]  = (_Float16)(attn_h[r] * 1.44269504f);
        biasC[e]   = attn_b[r];
        biasC[e+8] = 0.f;
    }
    f32x16 zeroC;
    #pragma unroll
    for (int r = 0; r < 16; ++r) zeroC[r] = 0.f;

    const char* ebase = (const char*)embLds;
    const unsigned laddr = (unsigned)lane * 16u;

    // ---- contiguous chunk: pairs [pbeg, pend), analytic i-run walk ----
    const int pbeg = wv * CHUNK;
    const int pend = (pbeg + CHUNK < NPAIR) ? pbeg + CHUNK : NPAIR;

    // decode (i,j) at pbeg (once per wave, wave-uniform)
    float tq = 9801.0f - 8.0f * (float)pbeg;
    int i = (int)((99.0f - sqrtf(tq)) * 0.5f);
    i = max(0, min(48, i));
    while (i < 48 && (49*(i+1) - (((i+1)*i)>>1)) <= pbeg) ++i;
    while (i > 0  && (49*i - ((i*(i-1))>>1)) > pbeg) --i;
    int j = i + 1 + (pbeg - (49*i - ((i*(i-1))>>1)));

    float num = 0.f, den = 0.f;
    int p = pbeg;
    while (p < pend) {                       // segment loop: one i-run per pass
        int len = FDIM - j;
        if (len > pend - p) len = pend - p;
        half8v ei = *(const half8v*)(ebase + (unsigned)(i * FBLK) + laddr);
        unsigned aj = (unsigned)(j * FBLK) + laddr;
        half8v ejn = *(const half8v*)(ebase + aj);   // 1-deep prefetch
        for (int n = 0; n < len; ++n) {
            half8v ej = ejn;
            aj += FBLK;
            ejn = *(const half8v*)(ebase + aj);      // overreads pad row at run end

            half8v prod = ei * ej;                   // B1 fragment (k=hi*8+e, col=b)
            f32x16 acc1 = mfma32x32x16f16(fragA1, prod, biasC);

            // pack regs 0..7 -> fp16, relu, feed MFMA2
            h16x2 q01 = __builtin_amdgcn_cvt_pkrtz(acc1[0], acc1[1]);
            h16x2 q23 = __builtin_amdgcn_cvt_pkrtz(acc1[2], acc1[3]);
            h16x2 q45 = __builtin_amdgcn_cvt_pkrtz(acc1[4], acc1[5]);
            h16x2 q67 = __builtin_amdgcn_cvt_pkrtz(acc1[6], acc1[7]);
            h16x8 pk = __builtin_shufflevector(
                           __builtin_shufflevector(q01, q23, 0, 1, 2, 3),
                           __builtin_shufflevector(q45, q67, 0, 1, 2, 3),
                           0, 1, 2, 3, 4, 5, 6, 7);
            half8v rf = __builtin_bit_cast(half8v, pk);
            half8v zf;
            #pragma unroll
            for (int e = 0; e < 8; ++e) zf[e] = (_Float16)0;
#if __has_builtin(__builtin_elementwise_max)
            rf = __builtin_elementwise_max(rf, zf);  // v_pk_max_f16 x4
#else
            #pragma unroll
            for (int e = 0; e < 8; ++e) rf[e] = rf[e] > (_Float16)0 ? rf[e] : (_Float16)0;
#endif
            f32x16 acc2 = mfma32x32x16f16(fragA2, rf, zeroC);  // every reg = s[b]

            float sc = __builtin_amdgcn_exp2f(acc2[0]);
            if (hi) den += sc;                       // lanes>=32: denominator
            else    num = fmaf(sc, acc1[8], num);    // acc1[8] = u (row 16)
        }
        p += len;
        ++i;
        j = i + 1;
    }

    if (hi) redLds[wv][col][1] = den;
    else    redLds[wv][col][0] = num;
    __syncthreads();

    if (t < BROWS) {
        float nn = 0.f, dd = 0.f;
        #pragma unroll
        for (int w = 0; w < NWAVE; ++w) { nn += redLds[w][t][0]; dd += redLds[w][t][1]; }
        out[b0 + t] = nn / dd + ylinLds[t];
    }
}

extern "C" void kernel_launch(void* const* d_in, const int* in_sizes, int n_in,
                              void* d_out, int out_size, void* d_ws, size_t ws_size,
                              hipStream_t stream) {
    const int*   feat_index = (const int*)  d_in[0];
    const float* feat_value = (const float*)d_in[1];
    const float* emb_table  = (const float*)d_in[2];
    const float* attn_w     = (const float*)d_in[3];
    const float* attn_b     = (const float*)d_in[4];
    const float* attn_h     = (const float*)d_in[5];
    const float* attn_p     = (const float*)d_in[6];
    const float* lin_w      = (const float*)d_in[7];
    const float* lin_b      = (const float*)d_in[8];
    float* outp = (float*)d_out;

    dim3 grid(out_size / BROWS);   // 256 blocks of 32 batch rows
    dim3 block(NTHREADS);
    afm_fwd<<<grid, block, 0, stream>>>(feat_index, feat_value, emb_table,
                                        attn_w, attn_b, attn_h, attn_p,
                                        lin_w, lin_b, outp);
}